// Round 1
// baseline (386.452 us; speedup 1.0000x reference)
//
#include <hip/hip_runtime.h>

// RWKV WKV forward scan.
// One thread per (b,h) channel: B*H = 16384 threads = 256 waves -> 1 wave/CU
// at block=64, grid=256 (maximal spread; scan is sequential over S).
// All exponent-domain quantities pre-scaled by log2(e) so exp() becomes raw
// v_exp_f32 (exp2) -- keeps per-step VALU issue under the HBM roofline with
// only 1 wave/CU. Loads double-buffered in registers (T=16 steps/chunk) to
// keep ~8KB/CU of global loads in flight across the serial recurrence.

#ifndef TCH
#define TCH 16
#endif

__device__ __forceinline__ float ex2(float x) { return __builtin_amdgcn_exp2f(x); }
__device__ __forceinline__ float rcpf(float x) { return __builtin_amdgcn_rcpf(x); }

// kts = k_t * log2e ; tfs = time_first * log2e ; tds = -exp(time_decay) * log2e
// m is carried scaled by log2e; num/den unscaled.
__device__ __forceinline__ float wkv_step(float kts, float vt, float tfs, float tds,
                                          float& m, float& num, float& den)
{
    const float ktf = kts + tfs;
    const float mo  = fmaxf(m, ktf);
    const float e1o = ex2(m - mo);          // args <= 0: no overflow
    const float e2o = ex2(ktf - mo);
    const float o   = (e1o * num + e2o * vt) * rcpf(e1o * den + e2o);
    const float mpd = m + tds;
    const float ms  = fmaxf(mpd, kts);
    const float e1s = ex2(mpd - ms);
    const float e2s = ex2(kts - ms);
    num = e1s * num + e2s * vt;
    den = e1s * den + e2s;
    m   = ms;
    return o;
}

__global__ __launch_bounds__(64, 1)
void wkv_fwd(const float* __restrict__ td_in, const float* __restrict__ kin,
             const float* __restrict__ tf_in, const float* __restrict__ vin,
             const float* __restrict__ m0, const float* __restrict__ n0,
             const float* __restrict__ d0,
             float* __restrict__ out, float* __restrict__ m_out,
             float* __restrict__ n_out, float* __restrict__ dn_out,
             int B, int S, int H)
{
    const int g = blockIdx.x * 64 + threadIdx.x;
    if (g >= B * H) return;
    const int b = g / H;
    const int h = g - b * H;

    constexpr float C  = 1.4426950408889634f;   // log2(e)
    constexpr float IC = 0.6931471805599453f;   // ln(2)

    const float tds = -ex2(td_in[h] * C) * C;   // log2e * (-exp(time_decay))
    const float tfs = tf_in[h] * C;

    float m   = m0[g] * C;
    float num = n0[g];
    float den = d0[g];

    const size_t base = (size_t)b * (size_t)S * (size_t)H + (size_t)h;
    const float* kp = kin + base;
    const float* vp = vin + base;
    float*       op = out + base;

    const int nc = S / TCH;

    float ka[TCH], va[TCH], kb[TCH], vb[TCH];

    if (nc > 0) {
        #pragma unroll
        for (int i = 0; i < TCH; ++i) {
            ka[i] = kp[(size_t)i * H];
            va[i] = vp[(size_t)i * H];
        }
    }

    int t = 0;
    for (int c = 0; c + 2 <= nc; c += 2) {
        // prefetch chunk c+1 into B while computing chunk c from A
        #pragma unroll
        for (int i = 0; i < TCH; ++i) {
            kb[i] = kp[(size_t)(t + TCH + i) * H];
            vb[i] = vp[(size_t)(t + TCH + i) * H];
        }
        #pragma unroll
        for (int i = 0; i < TCH; ++i) {
            op[(size_t)(t + i) * H] = wkv_step(ka[i] * C, va[i], tfs, tds, m, num, den);
        }
        t += TCH;
        // prefetch chunk c+2 into A (if it exists) while computing chunk c+1 from B
        if (c + 2 < nc) {
            #pragma unroll
            for (int i = 0; i < TCH; ++i) {
                ka[i] = kp[(size_t)(t + TCH + i) * H];
                va[i] = vp[(size_t)(t + TCH + i) * H];
            }
        }
        #pragma unroll
        for (int i = 0; i < TCH; ++i) {
            op[(size_t)(t + i) * H] = wkv_step(kb[i] * C, vb[i], tfs, tds, m, num, den);
        }
        t += TCH;
    }
    if (nc & 1) {
        // odd final chunk lives in A (initial load if nc==1, else last prefetch)
        #pragma unroll
        for (int i = 0; i < TCH; ++i) {
            op[(size_t)(t + i) * H] = wkv_step(ka[i] * C, va[i], tfs, tds, m, num, den);
        }
        t += TCH;
    }
    for (; t < S; ++t) {   // generic tail (unused for S=2048)
        const float kt = kp[(size_t)t * H];
        const float vt = vp[(size_t)t * H];
        op[(size_t)t * H] = wkv_step(kt * C, vt, tfs, tds, m, num, den);
    }

    m_out[g]  = m * IC;    // un-scale
    n_out[g]  = num;
    dn_out[g] = den;
}

extern "C" void kernel_launch(void* const* d_in, const int* in_sizes, int n_in,
                              void* d_out, int out_size, void* d_ws, size_t ws_size,
                              hipStream_t stream)
{
    const float* time_decay = (const float*)d_in[0];
    const float* key        = (const float*)d_in[1];
    const float* time_first = (const float*)d_in[2];
    const float* value      = (const float*)d_in[3];
    const float* max_state  = (const float*)d_in[4];
    const float* num_state  = (const float*)d_in[5];
    const float* den_state  = (const float*)d_in[6];

    const int H  = in_sizes[0];
    const int BH = in_sizes[4];
    const int B  = BH / H;
    const int S  = in_sizes[1] / BH;

    float* out    = (float*)d_out;
    float* m_out  = out + (size_t)B * (size_t)S * (size_t)H;
    float* n_out  = m_out + BH;
    float* dn_out = n_out + BH;

    const int grid = (BH + 63) / 64;
    wkv_fwd<<<grid, 64, 0, stream>>>(time_decay, key, time_first, value,
                                     max_state, num_state, den_state,
                                     out, m_out, n_out, dn_out, B, S, H);
}